// Round 5
// baseline (210.613 us; speedup 1.0000x reference)
//
#include <hip/hip_runtime.h>
#include <stdint.h>

#define CIN 256
#define HW4 784    // float4 per channel plane (56*56/4)
#define NB  32
#define NHO 28
#define NWO 28

// ---------------- K1: stats partials (blocks 0..2047) + weight packing (2048..2175) ----
// wq layout: [o][p][wv] -> wq[o*8 + p*4 + wv], so one o has both phases' rows in 64 B.
__global__ __launch_bounds__(256) void k_stage1(const float* __restrict__ x,
                          const float* __restrict__ w1, const float* __restrict__ w2,
                          double* __restrict__ part, unsigned long long* __restrict__ wq) {
    int blk = blockIdx.x;
    int tid = threadIdx.x;
    if (blk < 2048) {
        int c = blk >> 3, chunk = blk & 7;
        double s = 0.0, sq = 0.0;
        for (int bq = 0; bq < 4; ++bq) {
            int b = chunk * 4 + bq;
            const float4* base = (const float4*)x + (size_t)(b * CIN + c) * HW4;
            for (int i = tid; i < HW4; i += 256) {
                float4 v = base[i];
                double a0 = v.x, a1 = v.y, a2 = v.z, a3 = v.w;
                s  += (a0 + a1) + (a2 + a3);
                sq += (a0*a0 + a1*a1) + (a2*a2 + a3*a3);
            }
        }
        __shared__ double ls[256], lq[256];
        ls[tid] = s; lq[tid] = sq;
        __syncthreads();
        for (int off = 128; off > 0; off >>= 1) {
            if (tid < off) { ls[tid] += ls[tid+off]; lq[tid] += lq[tid+off]; }
            __syncthreads();
        }
        if (tid == 0) {   // transposed layout [chunk][c] for coalesced re-read
            part[(chunk*256 + c)*2]   = ls[0];
            part[(chunk*256 + c)*2+1] = lq[0];
        }
    } else {
        // weight packing: 2048 wave-tasks over 128 blocks * 4 waves * 4 tasks
        int wave = tid >> 6, l = tid & 63;
        int baseTask = ((blk - 2048)*4 + wave)*4;
        #pragma unroll
        for (int t = 0; t < 4; ++t) {
            int w_idx = baseTask + t;            // o*8 + p*4 + wv
            int o = w_idx >> 3, p = (w_idx >> 2) & 1, wv = w_idx & 3;
            const float* w = p ? w2 : w1;
            float v = w[o*256 + wv*64 + l];
            unsigned long long m = __ballot(v >= 0.0f);
            if (l == 0) wq[w_idx] = m;
        }
    }
}

// ---------------- K2: fused finalize + binarize + pack + popcount GEMM ----------------
// Block = (b, ho). LDS: stats 6KB + pred 15KB + apl 1.75KB = 22.8KB -> 7 blocks/CU.
// GEMM weights come from global via wave-uniform scalar loads (s_load), not LDS.
__global__ __launch_bounds__(256) void k_fused(const float* __restrict__ x,
    const double* __restrict__ part, const float* __restrict__ gamma,
    const float* __restrict__ beta, const unsigned long long* __restrict__ wq,
    float* __restrict__ out) {
    __shared__ double sm[256], ssg[256], sbt[256];
    __shared__ unsigned char pred[256*60];       // 28B phase0 + 28B phase1, stride 60
    __shared__ unsigned long long apl[224];      // [p][wo][g]
    int blk = blockIdx.x;
    int b = blk / NHO, ho = blk % NHO;
    int tid = threadIdx.x;

    // per-channel stats finalize from partials (coalesced: lane stride 16B)
    {
        int c = tid;
        double s = 0.0, sq = 0.0;
        for (int k = 0; k < 8; ++k) {
            s  += part[(k*256 + c)*2];
            sq += part[(k*256 + c)*2+1];
        }
        const double n = 100352.0;               // 32*3136
        double mean = s / n;
        double var  = sq / n - mean*mean;
        if (var < 0.0) var = 0.0;
        double invstd = 1.0 / sqrt(var + 1e-5);
        sm[c] = mean; ssg[c] = invstd * (double)gamma[c]; sbt[c] = (double)beta[c];
    }
    __syncthreads();

    // predicate phase: 7168 float4 over (c, r4); keep 2 of 4 pixels each (branchless)
    #pragma unroll 4
    for (int k = 0; k < 28; ++k) {
        int i4 = tid + k*256;
        int c = i4 / 28, r4 = i4 - c*28;         // r4<14: row 2ho (even cols); else row 2ho+1 (odd)
        float4 v = ((const float4*)x)[(size_t)(b*CIN + c)*HW4 + ho*28 + r4];
        double m = sm[c], sg = ssg[c], bt = sbt[c];
        bool e = (r4 < 14);
        float f0 = e ? v.x : v.y;                // even row: cols 4r4, 4r4+2 ; odd: 4r'+1, 4r'+3
        float f1 = e ? v.z : v.w;
        int off = c*60 + (e ? 2*r4 : 28 + 2*(r4 - 14));
        unsigned short bits;
        bits  = (((double)f0 - m)*sg + bt >= 0.0) ? 1u : 0u;
        bits |= (((double)f1 - m)*sg + bt >= 0.0) ? 0x100u : 0u;
        *(unsigned short*)&pred[off] = bits;
    }
    __syncthreads();

    // ballot phase: wave g owns channels [64g, 64g+64); lane stride 60B -> 2-way banks (free)
    {
        int g = tid >> 6, l = tid & 63;
        int c = g*64 + l;
        for (int p = 0; p < 2; ++p)
            for (int wo = 0; wo < NWO; ++wo) {
                unsigned char pr = pred[c*60 + p*28 + wo];
                unsigned long long mask = __ballot(pr != 0);
                if (l == 0) apl[p*112 + wo*4 + g] = mask;
            }
    }
    __syncthreads();

    // popcount GEMM: wave wid -> phase p = wid>>1, o-parity sub = wid&1; lane = wo.
    // Weight rows are wave-uniform -> scalar loads; activations live in 4 u64 regs.
    {
        int wid = __builtin_amdgcn_readfirstlane(tid >> 6);
        int p = wid >> 1, sub = wid & 1;
        int wi = tid & 63;
        if (wi < NWO) {
            unsigned long long a0[4];
            #pragma unroll
            for (int j = 0; j < 4; ++j) a0[j] = apl[p*112 + wi*4 + j];
            size_t outb = ((size_t)(b*512 + p*256))*784 + (size_t)ho*NWO + wi;
            #pragma unroll 4
            for (int og = 0; og < 128; ++og) {
                int o = og*2 + sub;
                const unsigned long long* wr = wq + o*8 + p*4;   // wave-uniform -> s_load
                int d = __popcll(a0[0]^wr[0]) + __popcll(a0[1]^wr[1])
                      + __popcll(a0[2]^wr[2]) + __popcll(a0[3]^wr[3]);
                out[outb + (size_t)o*784] = (float)(256 - 2*d);
            }
        }
    }
}

extern "C" void kernel_launch(void* const* d_in, const int* in_sizes, int n_in,
                              void* d_out, int out_size, void* d_ws, size_t ws_size,
                              hipStream_t stream) {
    const float* x     = (const float*)d_in[0];
    const float* gamma = (const float*)d_in[1];
    const float* beta  = (const float*)d_in[2];
    const float* w1    = (const float*)d_in[3];
    const float* w2    = (const float*)d_in[4];
    float* out = (float*)d_out;

    char* ws = (char*)d_ws;
    double* part = (double*)ws;                                 // 2048*2 doubles = 32 KB
    unsigned long long* wq = (unsigned long long*)(ws + 40960); // 16 KB

    k_stage1<<<2176, 256, 0, stream>>>(x, w1, w2, part, wq);
    k_fused<<<NB*NHO, 256, 0, stream>>>(x, part, gamma, beta, wq, out);
}

// Round 6
// 204.707 us; speedup vs baseline: 1.0288x; 1.0288x over previous
//
#include <hip/hip_runtime.h>
#include <stdint.h>

#define CIN 256
#define HW4 784    // float4 per channel plane (56*56/4)
#define NB  32
#define NHO 28
#define NWO 28

// ---------------- K1: stats partials (blocks 0..2047) + weight packing (2048..2175) ----
// wq layout: [o][p][wv] -> wq[o*8 + p*4 + wv], so one o has both phases' rows in 64 B.
__global__ __launch_bounds__(256) void k_stage1(const float* __restrict__ x,
                          const float* __restrict__ w1, const float* __restrict__ w2,
                          double* __restrict__ part, unsigned long long* __restrict__ wq) {
    int blk = blockIdx.x;
    int tid = threadIdx.x;
    if (blk < 2048) {
        int c = blk >> 3, chunk = blk & 7;
        double s = 0.0, sq = 0.0;
        for (int bq = 0; bq < 4; ++bq) {
            int b = chunk * 4 + bq;
            const float4* base = (const float4*)x + (size_t)(b * CIN + c) * HW4;
            for (int i = tid; i < HW4; i += 256) {
                float4 v = base[i];
                double a0 = v.x, a1 = v.y, a2 = v.z, a3 = v.w;
                s  += (a0 + a1) + (a2 + a3);
                sq += (a0*a0 + a1*a1) + (a2*a2 + a3*a3);
            }
        }
        __shared__ double ls[256], lq[256];
        ls[tid] = s; lq[tid] = sq;
        __syncthreads();
        for (int off = 128; off > 0; off >>= 1) {
            if (tid < off) { ls[tid] += ls[tid+off]; lq[tid] += lq[tid+off]; }
            __syncthreads();
        }
        if (tid == 0) {   // transposed layout [chunk][c] for coalesced re-read
            part[(chunk*256 + c)*2]   = ls[0];
            part[(chunk*256 + c)*2+1] = lq[0];
        }
    } else {
        // weight packing: 2048 wave-tasks over 128 blocks * 4 waves * 4 tasks
        int wave = tid >> 6, l = tid & 63;
        int baseTask = ((blk - 2048)*4 + wave)*4;
        #pragma unroll
        for (int t = 0; t < 4; ++t) {
            int w_idx = baseTask + t;            // o*8 + p*4 + wv
            int o = w_idx >> 3, p = (w_idx >> 2) & 1, wv = w_idx & 3;
            const float* w = p ? w2 : w1;
            float v = w[o*256 + wv*64 + l];
            unsigned long long m = __ballot(v >= 0.0f);
            if (l == 0) wq[w_idx] = m;
        }
    }
}

// ---------------- K2: fused finalize + binarize + pack + popcount GEMM ----------------
// Block = (b, ho). LDS: stats 6KB + pred 15KB + apl 1.75KB = 22.8KB -> up to 7 blocks/CU.
__global__ __launch_bounds__(256, 6) void k_fused(const float* __restrict__ x,
    const double* __restrict__ part, const float* __restrict__ gamma,
    const float* __restrict__ beta, const unsigned long long* __restrict__ wq,
    float* __restrict__ out) {
    __shared__ double sm[256], ssg[256], sbt[256];
    __shared__ unsigned char pred[256*60];       // 28B phase0 + 28B phase1, stride 60
    __shared__ unsigned long long apl[224];      // [p][wo][g]
    int blk = blockIdx.x;
    int b = blk / NHO, ho = blk % NHO;
    int tid = threadIdx.x;

    // per-channel stats finalize from partials (coalesced: lane stride 16B)
    {
        int c = tid;
        double s = 0.0, sq = 0.0;
        for (int k = 0; k < 8; ++k) {
            s  += part[(k*256 + c)*2];
            sq += part[(k*256 + c)*2+1];
        }
        const double n = 100352.0;               // 32*3136
        double mean = s / n;
        double var  = sq / n - mean*mean;
        if (var < 0.0) var = 0.0;
        double invstd = 1.0 / sqrt(var + 1e-5);
        sm[c] = mean; ssg[c] = invstd * (double)gamma[c]; sbt[c] = (double)beta[c];
    }
    __syncthreads();

    // predicate phase: 7168 float4 over (c, r4); keep 2 of 4 pixels each (branchless)
    #pragma unroll 4
    for (int k = 0; k < 28; ++k) {
        int i4 = tid + k*256;
        int c = i4 / 28, r4 = i4 - c*28;         // r4<14: row 2ho (even cols); else row 2ho+1 (odd)
        float4 v = ((const float4*)x)[(size_t)(b*CIN + c)*HW4 + ho*28 + r4];
        double m = sm[c], sg = ssg[c], bt = sbt[c];
        bool e = (r4 < 14);
        float f0 = e ? v.x : v.y;                // even row: cols 4r4, 4r4+2 ; odd: 4r'+1, 4r'+3
        float f1 = e ? v.z : v.w;
        int off = c*60 + (e ? 2*r4 : 28 + 2*(r4 - 14));
        unsigned short bits;
        bits  = (((double)f0 - m)*sg + bt >= 0.0) ? 1u : 0u;
        bits |= (((double)f1 - m)*sg + bt >= 0.0) ? 0x100u : 0u;
        *(unsigned short*)&pred[off] = bits;
    }
    __syncthreads();

    // ballot phase: wave g owns channels [64g, 64g+64); u16 read = 2 wo at once
    {
        int g = tid >> 6, l = tid & 63;
        int c = g*64 + l;
        for (int p = 0; p < 2; ++p)
            for (int wop = 0; wop < 14; ++wop) {
                unsigned short v = *(const unsigned short*)&pred[c*60 + p*28 + 2*wop];
                unsigned long long m0 = __ballot((v & 0x0001u) != 0);
                unsigned long long m1 = __ballot((v & 0x0100u) != 0);
                if (l == 0) {
                    apl[p*112 + (2*wop)*4   + g] = m0;
                    apl[p*112 + (2*wop+1)*4 + g] = m1;
                }
            }
    }
    __syncthreads();

    // popcount GEMM: wave = (p, sub); lane halves cover o = og*4 + sub*2 + {0,1}.
    // Per iter: 2 output planes, stores are two contiguous 112B runs.
    {
        int wid = tid >> 6;
        int p = wid >> 1, sub = wid & 1;
        int half = (tid >> 5) & 1;
        int wi = tid & 31;
        if (wi < NWO) {
            unsigned long long a0[4];
            #pragma unroll
            for (int j = 0; j < 4; ++j) a0[j] = apl[p*112 + wi*4 + j];
            int obase = sub*2 + half;            // o = og*4 + obase
            const unsigned long long* wr = wq + (size_t)obase*8 + p*4;
            float* outp = out + ((size_t)(b*512 + p*256 + obase))*784 + (size_t)ho*NWO + wi;
            #pragma unroll 4
            for (int og = 0; og < 64; ++og) {
                int d = __popcll(a0[0]^wr[0]) + __popcll(a0[1]^wr[1])
                      + __popcll(a0[2]^wr[2]) + __popcll(a0[3]^wr[3]);
                *outp = (float)(256 - 2*d);
                wr += 32;                        // 4 o-steps * 8 u64
                outp += 4*784;
            }
        }
    }
}

extern "C" void kernel_launch(void* const* d_in, const int* in_sizes, int n_in,
                              void* d_out, int out_size, void* d_ws, size_t ws_size,
                              hipStream_t stream) {
    const float* x     = (const float*)d_in[0];
    const float* gamma = (const float*)d_in[1];
    const float* beta  = (const float*)d_in[2];
    const float* w1    = (const float*)d_in[3];
    const float* w2    = (const float*)d_in[4];
    float* out = (float*)d_out;

    char* ws = (char*)d_ws;
    double* part = (double*)ws;                                 // 2048*2 doubles = 32 KB
    unsigned long long* wq = (unsigned long long*)(ws + 40960); // 16 KB

    k_stage1<<<2176, 256, 0, stream>>>(x, w1, w2, part, wq);
    k_fused<<<NB*NHO, 256, 0, stream>>>(x, part, gamma, beta, wq, out);
}